// Round 6
// baseline (8941.870 us; speedup 1.0000x reference)
//
#include <hip/hip_runtime.h>

#define B_SZ 2048
#define FEAT 840
#define HID  256
#define LAT  128
#define NQ   12
#define NEMB 512

#define T_SUB 60    // 14 tiles x 60 = 840 exactly; lanes 0..59 active
#define NTILE 14
#define H2STR 61    // h2 stride ODD -> reducer reads conflict-free
#define W1B1_FLOATS (HID * 4)                    // [c2][wA,wB,wC,b1] = 1024
#define W2W_FLOATS  (HID * 384)                  // [wid][c2][48]     = 98304
#define WS_FLOATS   (W1B1_FLOATS + W2W_FLOATS)   // 99328 floats = 397312 B

// numpy pairwise 8-accumulator combine: ((r0+r1)+(r2+r3))+((r4+r5)+(r6+r7))
__device__ __forceinline__ float np8_combine(const float* r) {
    float sA = __fadd_rn(r[0], r[1]);
    float sB = __fadd_rn(r[2], r[3]);
    float sC = __fadd_rn(r[4], r[5]);
    float sD = __fadd_rn(r[6], r[7]);
    return __fadd_rn(__fadd_rn(sA, sB), __fadd_rn(sC, sD));
}

// ---- repack: ws = [w1b1: 256x4][w2w: wave-major [wid][c2][lr*3+k]] ----
__global__ __launch_bounds__(256) void w2r_kernel(const float* __restrict__ w2,
                                                  const float* __restrict__ w1,
                                                  const float* __restrict__ b1,
                                                  float* __restrict__ ws)
{
    int p = blockIdx.x * 256 + threadIdx.x;
    if (p < W1B1_FLOATS) {
        int c2 = p >> 2, r = p & 3;
        ws[p] = (r < 3) ? w1[c2*3 + r] : b1[c2];
    } else if (p < WS_FLOATS) {
        int q   = p - W1B1_FLOATS;
        int wid = q / 12288, rem = q - wid * 12288;   // 256*48 = 12288
        int c2  = rem / 48,  r   = rem - c2 * 48;
        int lr  = r / 3,     k   = r - lr * 3;
        int l   = wid * 16 + lr;
        ws[p] = w2[(size_t)l * 768 + c2 * 3 + k];     // w2[l][c2][k]
    }
}

// conv over all 256 c2 for one t-tile; h1 window recomputed in registers
// (exact phase-A op sequence: fadd(fadd(fmul,fmul),fmul)+b1, relu, zero halo)
// -> inner loop has NO LDS ops: lgkmcnt domain is pure-SMEM (weights),
// so counted/batched waits pipeline instead of full drains every c2.
template <int USE_WR, bool EDGE>
__device__ __forceinline__ void conv_c2(
    int wid, int t,
    float xm2, float xm1, float x0, float xp1, float xp2,
    const float* __restrict__ w1b1, const float* __restrict__ w2wv,
    const float* __restrict__ w1,   const float* __restrict__ b1,
    const float* __restrict__ w2,
    float acc[16][3])
{
    // H0 = h1(c2, t-1), H1 = h1(c2, t), H2 = h1(c2, t+1)
    const bool v0 = !EDGE || (t >= 1);           // t-1 in [0, FEAT)
    const bool v2 = !EDGE || (t <= FEAT - 2);    // t+1 in [0, FEAT)
#pragma unroll 2
    for (int c2 = 0; c2 < HID; ++c2) {
        float wA, wB, wC, bc;
        if (USE_WR) {
            const float4 wb = *(const float4*)(w1b1 + c2*4);
            wA = wb.x; wB = wb.y; wC = wb.z; bc = wb.w;
        } else {
            wA = w1[c2*3+0]; wB = w1[c2*3+1]; wC = w1[c2*3+2]; bc = b1[c2];
        }
        float s0 = __fadd_rn(__fadd_rn(__fmul_rn(wA, xm2), __fmul_rn(wB, xm1)),
                             __fmul_rn(wC, x0));
        s0 = __fadd_rn(s0, bc);
        float H0 = s0 > 0.f ? s0 : 0.f;
        float s1 = __fadd_rn(__fadd_rn(__fmul_rn(wA, xm1), __fmul_rn(wB, x0)),
                             __fmul_rn(wC, xp1));
        s1 = __fadd_rn(s1, bc);
        float H1 = s1 > 0.f ? s1 : 0.f;
        float s2 = __fadd_rn(__fadd_rn(__fmul_rn(wA, x0), __fmul_rn(wB, xp1)),
                             __fmul_rn(wC, xp2));
        s2 = __fadd_rn(s2, bc);
        float H2 = s2 > 0.f ? s2 : 0.f;
        if (EDGE) {
            if (!v0) H0 = 0.f;    // zero halo, matches phase-A OOB rows
            if (!v2) H2 = 0.f;
        }
        if (USE_WR) {
            const float* __restrict__ wv = w2wv + (size_t)c2 * 48;
#pragma unroll
            for (int l = 0; l < 16; ++l) {
                acc[l][0] = __fmaf_rn(wv[l*3+0], H0, acc[l][0]);
                acc[l][1] = __fmaf_rn(wv[l*3+1], H1, acc[l][1]);
                acc[l][2] = __fmaf_rn(wv[l*3+2], H2, acc[l][2]);
            }
        } else {
#pragma unroll
            for (int l = 0; l < 16; ++l) {
                const float* __restrict__ wr =
                    w2 + (size_t)(wid*16 + l)*768 + c2*3;
                acc[l][0] = __fmaf_rn(wr[0], H0, acc[l][0]);
                acc[l][1] = __fmaf_rn(wr[1], H1, acc[l][1]);
                acc[l][2] = __fmaf_rn(wr[2], H2, acc[l][2]);
            }
        }
    }
}

// numpy-ordered mean reducer: one tile's 60 t-values into pairwise leaves.
// chunked loads (10 at a time) break the load-latency serial chain; add order
// is the strict sequential tt = 0..59 -> bit-exact.
__device__ __forceinline__ void reduce_tile(
    const float* __restrict__ h2s, int tid,
    float racc[8], int& leaf_id, int& leaf_pos, float* __restrict__ leafs)
{
    for (int g = 0; g < T_SUB; g += 10) {
        float v[10];
#pragma unroll
        for (int m = 0; m < 10; ++m)
            v[m] = h2s[tid*H2STR + g + m];
#pragma unroll
        for (int m = 0; m < 10; ++m) {
            float vv = v[m];
            int j = leaf_pos & 7;
            racc[j] = (leaf_pos < 8) ? vv : __fadd_rn(racc[j], vv);
            ++leaf_pos;
            int llen = (leaf_id == 7) ? 112 : 104;
            if (leaf_pos == llen) {
                leafs[tid*8 + leaf_id] = np8_combine(racc);
                ++leaf_id; leaf_pos = 0;
            }
        }
    }
}

// ---------------- encoder, numpy-f32 bit-faithful ----------------
// 512 threads = 8 waves; wave w owns l = w*16..w*16+15; lane = t in tile.
// No phase A / h1s: conv1 recomputed in registers from 5 x-values per lane.
// Weights wave-uniform -> s_load (pure-SMEM lgkmcnt in the hot loop).
// Reducer is NON-overlapped (round-5 overlap caused steady-state output
// divergence): per tile conv -> h2 write (wave-private rows) -> barrier ->
// reduce -> barrier. No concurrent LDS read/write anywhere.
// acc chain: c2 = 0..255 ascending per (l,t,k); h2 = relu((k0+k1)+k2 + b2);
// identical op order to prior rounds -> bit-exact. (No min-waves bound!)
template <int USE_WR>
__global__ __launch_bounds__(512) void enc_kernel(
    const float* __restrict__ x,  const float* __restrict__ w1,
    const float* __restrict__ b1, const float* __restrict__ w2,
    const float* __restrict__ ws,
    const float* __restrict__ b2, float* __restrict__ zout)
{
    __shared__ float h2s[LAT * H2STR];      // 31232 B
    __shared__ float leafs[LAT * 8];        // 4096 B  => 35328 B total

    const int tid  = threadIdx.x;
    const int b    = blockIdx.x;
    const int lane = tid & 63;                                   // time pos
    const int wid  = __builtin_amdgcn_readfirstlane(tid >> 6);   // wave id

    const float* __restrict__ xrow  = x + (size_t)b * FEAT;
    const float* __restrict__ w1b1  = ws;                        // [c2][4]
    const float* __restrict__ w2wv  = ws + W1B1_FLOATS + (size_t)wid * 12288;

    // b2 for this wave's 16 output channels (uniform -> scalar regs)
    float b2v[16];
#pragma unroll
    for (int j = 0; j < 16; ++j) b2v[j] = b2[wid*16 + j];

    // numpy pairwise-840 leaf state (threads 0..127, one l each)
    float racc[8];
    int leaf_id = 0, leaf_pos = 0;
#pragma unroll
    for (int j = 0; j < 8; ++j) racc[j] = 0.f;

    for (int ti = 0; ti < NTILE; ++ti) {
        const int t0 = ti * T_SUB;
        const int t  = t0 + lane;
        const bool edge = (ti == 0) | (ti == NTILE - 1);

        // x window for this lane (edge tiles bounds-check; middle tiles
        // max idx = 720+63+2 = 785 < 840, min idx = 60-2 = 58 >= 0)
        float xm2, xm1, x0, xp1, xp2;
        if (edge) {
            int i0 = t - 2;
            xm2 = (i0 >= 0     && i0 < FEAT)     ? xrow[i0]     : 0.f;
            xm1 = (i0 >= -1    && i0 < FEAT - 1) ? xrow[i0 + 1] : 0.f;
            x0  = (i0 >= -2    && i0 < FEAT - 2) ? xrow[i0 + 2] : 0.f;
            xp1 = (i0 >= -3    && i0 < FEAT - 3) ? xrow[i0 + 3] : 0.f;
            xp2 = (i0 >= -4    && i0 < FEAT - 4) ? xrow[i0 + 4] : 0.f;
        } else {
            const float* __restrict__ xc = xrow + (t - 2);
            xm2 = xc[0]; xm1 = xc[1]; x0 = xc[2]; xp1 = xc[3]; xp2 = xc[4];
        }

        float acc[16][3];
#pragma unroll
        for (int l = 0; l < 16; ++l)
#pragma unroll
            for (int k = 0; k < 3; ++k) acc[l][k] = 0.f;

        if (edge)
            conv_c2<USE_WR, true >(wid, t, xm2, xm1, x0, xp1, xp2,
                                   w1b1, w2wv, w1, b1, w2, acc);
        else
            conv_c2<USE_WR, false>(wid, t, xm2, xm1, x0, xp1, xp2,
                                   w1b1, w2wv, w1, b1, w2, acc);

        // h2 = fl(fl(k0+k1)+k2) + b2, relu -> wave-private h2s rows
        if (lane < T_SUB) {
#pragma unroll
            for (int l = 0; l < 16; ++l) {
                float hh = __fadd_rn(__fadd_rn(acc[l][0], acc[l][1]), acc[l][2]);
                hh = __fadd_rn(hh, b2v[l]);
                hh = hh > 0.f ? hh : 0.f;
                h2s[(wid*16 + l)*H2STR + lane] = hh;
            }
        }
        __syncthreads();   // h2 visible to reducer

        if (tid < LAT)
            reduce_tile(h2s, tid, racc, leaf_id, leaf_pos, leafs);
        __syncthreads();   // reducer reads done before next tile's writes
    }

    // numpy pairwise-840 recombination
    if (tid < LAT) {
        const float* L = &leafs[tid*8];
        float s0 = __fadd_rn(L[0], L[1]);
        float s1 = __fadd_rn(L[2], L[3]);
        float sA = __fadd_rn(s0, s1);
        float s2 = __fadd_rn(L[4], L[5]);
        float s3 = __fadd_rn(L[6], L[7]);
        float sB = __fadd_rn(s2, s3);
        float tot = __fadd_rn(sA, sB);
        zout[(size_t)b*LAT + tid] = __fdiv_rn(tot, 840.0f);
    }
}

// ---------------- RVQ, numpy-f32 bit-faithful ----------------
__global__ __launch_bounds__(256) void rvq32_kernel(
    const float* __restrict__ cb, const float* __restrict__ z,
    float* __restrict__ zqout, float* __restrict__ oidx)
{
    __shared__ float rr[LAT];
    __shared__ float Ash;
    __shared__ float redd[256];
    __shared__ int   rede[256];
    __shared__ float sredd[64];
    __shared__ int   srede[64];
    __shared__ int   beste;
    __shared__ float qv[NQ * LAT];

    const int tid = threadIdx.x;
    const int b   = blockIdx.x;

    if (tid < LAT) rr[tid] = z[(size_t)b*LAT + tid];
    __syncthreads();

    for (int q = 0; q < NQ; ++q) {
        const float* __restrict__ cbq = cb + (size_t)q * NEMB * LAT;

        if (tid == 0) {
            float r8[8];
#pragma unroll
            for (int j = 0; j < 8; ++j) r8[j] = __fmul_rn(rr[j], rr[j]);
            for (int i = 8; i < LAT; i += 8)
#pragma unroll
                for (int j = 0; j < 8; ++j)
                    r8[j] = __fadd_rn(r8[j], __fmul_rn(rr[i+j], rr[i+j]));
            Ash = np8_combine(r8);
        }
        __syncthreads();

        float dmin = 0.f; int emin = 0;
#pragma unroll
        for (int h = 0; h < 2; ++h) {
            int e = 2*tid + h;
            const float* __restrict__ cp = cbq + (size_t)e*LAT;
            float dot = 0.f;
            float c8[8];
#pragma unroll
            for (int j = 0; j < 8; ++j) {
                float c = cp[j];
                c8[j] = __fmul_rn(c, c);
                dot = __fmaf_rn(c, rr[j], dot);
            }
            for (int i = 8; i < LAT; i += 8)
#pragma unroll
                for (int j = 0; j < 8; ++j) {
                    float c = cp[i+j];
                    dot = __fmaf_rn(c, rr[i+j], dot);
                    c8[j] = __fadd_rn(c8[j], __fmul_rn(c, c));
                }
            float cn = np8_combine(c8);
            float G  = __fmul_rn(2.0f, dot);
            float d  = __fadd_rn(__fsub_rn(Ash, G), cn);
            if (h == 0) { dmin = d; emin = e; }
            else if (d < dmin) { dmin = d; emin = e; }
        }
        redd[tid] = dmin; rede[tid] = emin;
        __syncthreads();

        if (tid < 64) {
            float bb = redd[tid*4]; int ee = rede[tid*4];
            for (int j = 1; j < 4; ++j) {
                float dj = redd[tid*4 + j];
                if (dj < bb) { bb = dj; ee = rede[tid*4 + j]; }
            }
            sredd[tid] = bb; srede[tid] = ee;
        }
        __syncthreads();
        if (tid == 0) {
            float bb = sredd[0]; int ee = srede[0];
            for (int j = 1; j < 64; ++j) {
                float dj = sredd[j];
                if (dj < bb) { bb = dj; ee = srede[j]; }
            }
            beste = ee;
            oidx[(size_t)b*NQ + q] = (float)ee;
        }
        __syncthreads();

        if (tid < LAT) {
            float cv = cbq[(size_t)beste*LAT + tid];
            qv[q*LAT + tid] = cv;
            rr[tid] = __fsub_rn(rr[tid], cv);
        }
        __syncthreads();
    }

    if (tid < LAT) {
        float s = qv[tid];
        for (int s2 = 1; s2 < NQ; ++s2)
            s = __fadd_rn(s, qv[s2*LAT + tid]);
        zqout[(size_t)b*LAT + tid] = s;
    }
}

extern "C" void kernel_launch(void* const* d_in, const int* in_sizes, int n_in,
                              void* d_out, int out_size, void* d_ws, size_t ws_size,
                              hipStream_t stream)
{
    (void)in_sizes; (void)n_in; (void)out_size;
    const float* x  = (const float*)d_in[0];
    const float* w1 = (const float*)d_in[1];
    const float* b1 = (const float*)d_in[2];
    const float* w2 = (const float*)d_in[3];
    const float* b2 = (const float*)d_in[4];
    const float* cb = (const float*)d_in[5];

    float* out  = (float*)d_out;
    float* zq   = out;                         // 2048*1*128 floats
    float* oidx = out + (size_t)B_SZ * LAT;    // 2048*1*12 floats

    const size_t ws_bytes = (size_t)WS_FLOATS * sizeof(float);   // 397312

    if (ws_size >= ws_bytes) {
        float* wsp = (float*)d_ws;
        w2r_kernel<<<WS_FLOATS/256, 256, 0, stream>>>(w2, w1, b1, wsp);
        enc_kernel<1><<<B_SZ, 512, 0, stream>>>(x, w1, b1, w2, wsp, b2, zq);
    } else {
        enc_kernel<0><<<B_SZ, 512, 0, stream>>>(x, w1, b1, w2, nullptr, b2, zq);
    }
    rvq32_kernel<<<B_SZ, 256, 0, stream>>>(cb, zq, zq, oidx);
}

// Round 7
// 5924.743 us; speedup vs baseline: 1.5092x; 1.5092x over previous
//
#include <hip/hip_runtime.h>

#define B_SZ 2048
#define FEAT 840
#define HID  256
#define LAT  128
#define NQ   12
#define NEMB 512

#define T_SUB 40    // 21 tiles x 40 = 840
#define NTILE 21
#define HSTR  46    // h1 row stride (40+2 halo, padded EVEN -> float2 reads align)
#define H2STR 41    // h2 stride ODD -> reducer reads conflict-free (aliased in h1s)
#define CHALF 128   // c2 half-size: h1s holds one half of channels at a time

// numpy pairwise 8-accumulator combine: ((r0+r1)+(r2+r3))+((r4+r5)+(r6+r7))
__device__ __forceinline__ float np8_combine(const float* r) {
    float sA = __fadd_rn(r[0], r[1]);
    float sB = __fadd_rn(r[2], r[3]);
    float sC = __fadd_rn(r[4], r[5]);
    float sD = __fadd_rn(r[6], r[7]);
    return __fadd_rn(__fadd_rn(sA, sB), __fadd_rn(sC, sD));
}

// ---------------- w2 repack, j-major: w2r[c2][ly][j*3+k] ----------------
// (identical to the round-0/2 repack; ly in [0,32), j in [0,4), k in [0,3))
__global__ __launch_bounds__(256) void w2r_kernel(const float* __restrict__ w2,
                                                  float* __restrict__ w2r)
{
    int p = blockIdx.x * 256 + threadIdx.x;          // [0, 256*384)
    if (p >= HID * 384) return;
    int c2 = p / 384, r = p - c2 * 384;
    int ly = r / 12, jk = r - ly * 12;
    int j = jk / 3, k = jk - j * 3;
    w2r[p] = w2[(size_t)(ly*4 + j)*768 + c2*3 + k];
}

// ---------------- encoder, numpy-f32 bit-faithful ----------------
// 128 threads = 2 waves. Thread (ly = tid>>2, tx = tid&3) owns output
// channels l = ly*4..ly*4+3 at t-positions u0..u0+9 (u0 = tx*10):
// 4l x 10t x 3k = 120 accumulators -> 12 weight floats feed 120 FMAs
// (2x the FMA-per-load density of the 6.0ms round-0/2 structure; weight
// traffic per FMA halved -- the measured wall across rounds 0-6).
// Weights via float4 vector loads from w2r (deep vmcnt pipelining);
// h via 6x ds_read_b64 per c2 (HSTR even => 8B aligned).
// c2 in two halves of 128 (h1s halved); acc carried across halves ->
// per-(l,t,k) fma chain runs c2 = 0..255 ascending; h2 = relu((k0+k1)+k2+b2);
// reducer strict-sequential numpy leaves: bit-exact vs rounds 0/2/6.
// (Round-1 lesson: NO min-waves launch-bounds arg.)
template <int USE_WR>
__global__ __launch_bounds__(128) void enc_kernel(
    const float* __restrict__ x,  const float* __restrict__ w1,
    const float* __restrict__ b1, const float* __restrict__ w2,
    const float* __restrict__ w2r,
    const float* __restrict__ b2, float* __restrict__ zout)
{
    __shared__ float xp[FEAT + 4];          // 3376 B
    __shared__ float h1s[CHALF * HSTR];     // 23552 B; h2 tile aliased here
    __shared__ float leafs[LAT * 8];        // 4096 B   => 31024 B total

    const int tid = threadIdx.x;            // [0,128)
    const int b   = blockIdx.x;
    const int tx  = tid & 3;                // t-group (10 t's)
    const int ly  = tid >> 2;               // l-group (4 l's)
    const int u0  = tx * 10;

    // conv1 weights: this thread computes channel ach (= tid) of each half
    const int ach = tid;
    float w1v[2][3], b1v[2];
#pragma unroll
    for (int hf = 0; hf < 2; ++hf) {
        int c = hf * CHALF + ach;
        w1v[hf][0] = w1[c*3 + 0];
        w1v[hf][1] = w1[c*3 + 1];
        w1v[hf][2] = w1[c*3 + 2];
        b1v[hf]    = b1[c];
    }
    float b2v[4];
#pragma unroll
    for (int j = 0; j < 4; ++j) b2v[j] = b2[ly*4 + j];

    for (int i = tid; i < FEAT + 2; i += 128)
        xp[i] = (i >= 1 && i <= FEAT) ? x[(size_t)b*FEAT + i - 1] : 0.f;

    // numpy pairwise-840 leaf state (all 128 threads, one l each)
    float racc[8];
    int leaf_id = 0, leaf_pos = 0;
#pragma unroll
    for (int j = 0; j < 8; ++j) racc[j] = 0.f;

    __syncthreads();
    for (int t0 = 0; t0 < FEAT; t0 += T_SUB) {
        const bool edge = (t0 == 0) | (t0 + T_SUB == FEAT);

        float sk[4][10][3];
#pragma unroll
        for (int j = 0; j < 4; ++j)
#pragma unroll
            for (int i = 0; i < 10; ++i)
#pragma unroll
                for (int k = 0; k < 3; ++k) sk[j][i][k] = 0.f;

#pragma unroll
        for (int hf = 0; hf < 2; ++hf) {
            // ---- phase A (half hf): h1[ach][tp], tp = 0..41 ----
            {
                const float wA = w1v[hf][0], wB = w1v[hf][1], wC = w1v[hf][2];
                const float bb = b1v[hf];
                if (edge) {
                    for (int tp = 0; tp < T_SUB + 2; ++tp) {
                        int tg = t0 - 1 + tp;
                        float v = 0.f;
                        if (tg >= 0 && tg < FEAT) {
                            float s = __fadd_rn(__fadd_rn(__fmul_rn(wA, xp[tg]),
                                                          __fmul_rn(wB, xp[tg+1])),
                                                __fmul_rn(wC, xp[tg+2]));
                            s = __fadd_rn(s, bb);
                            v = s > 0.f ? s : 0.f;
                        }
                        h1s[ach*HSTR + tp] = v;
                    }
                } else {
#pragma unroll 6
                    for (int tp = 0; tp < T_SUB + 2; ++tp) {
                        int tg = t0 - 1 + tp;
                        float s = __fadd_rn(__fadd_rn(__fmul_rn(wA, xp[tg]),
                                                      __fmul_rn(wB, xp[tg+1])),
                                            __fmul_rn(wC, xp[tg+2]));
                        s = __fadd_rn(s, bb);
                        h1s[ach*HSTR + tp] = s > 0.f ? s : 0.f;
                    }
                }
            }
            __syncthreads();

            // ---- phase B (half hf): c2 = hf*128 + cc ascending ----
            if (USE_WR) {
                const float* __restrict__ wbase =
                    w2r + (size_t)(hf*CHALF)*384 + ly*12;
#pragma unroll 2
                for (int cc = 0; cc < CHALF; ++cc) {
                    const float4* __restrict__ wq =
                        (const float4*)(wbase + (size_t)cc*384);
                    float4 A0 = wq[0], A1 = wq[1], A2 = wq[2];
                    float w_[12];
                    w_[0]=A0.x; w_[1]=A0.y; w_[2]=A0.z; w_[3]=A0.w;
                    w_[4]=A1.x; w_[5]=A1.y; w_[6]=A1.z; w_[7]=A1.w;
                    w_[8]=A2.x; w_[9]=A2.y; w_[10]=A2.z; w_[11]=A2.w;

                    const float2* __restrict__ hq =
                        (const float2*)(&h1s[cc*HSTR + u0]);   // even idx: aligned
                    float2 q0=hq[0], q1=hq[1], q2=hq[2], q3=hq[3], q4=hq[4], q5=hq[5];
                    float hv[12] = {q0.x,q0.y,q1.x,q1.y,q2.x,q2.y,
                                    q3.x,q3.y,q4.x,q4.y,q5.x,q5.y};
#pragma unroll
                    for (int j = 0; j < 4; ++j)
#pragma unroll
                        for (int i = 0; i < 10; ++i)
#pragma unroll
                            for (int k = 0; k < 3; ++k)
                                sk[j][i][k] = __fmaf_rn(w_[j*3+k], hv[i+k],
                                                        sk[j][i][k]);
                }
            } else {
                for (int cc = 0; cc < CHALF; ++cc) {
                    int c2 = hf*CHALF + cc;
                    const float* hp = &h1s[cc*HSTR + u0];
                    float hv[12];
#pragma unroll
                    for (int m = 0; m < 12; ++m) hv[m] = hp[m];
#pragma unroll
                    for (int j = 0; j < 4; ++j) {
                        float wa = w2[(size_t)(ly*4+j)*768 + c2*3 + 0];
                        float wb = w2[(size_t)(ly*4+j)*768 + c2*3 + 1];
                        float wc = w2[(size_t)(ly*4+j)*768 + c2*3 + 2];
#pragma unroll
                        for (int i = 0; i < 10; ++i) {
                            sk[j][i][0] = __fmaf_rn(wa, hv[i],   sk[j][i][0]);
                            sk[j][i][1] = __fmaf_rn(wb, hv[i+1], sk[j][i][1]);
                            sk[j][i][2] = __fmaf_rn(wc, hv[i+2], sk[j][i][2]);
                        }
                    }
                }
            }
            __syncthreads();   // h1s reads done before next half / h2 overwrite
        }

        // h2 = fl(fl(k0+k1)+k2) + b2, relu -> aliased LDS (h1s region)
#pragma unroll
        for (int j = 0; j < 4; ++j)
#pragma unroll
            for (int i = 0; i < 10; ++i) {
                float hh = __fadd_rn(__fadd_rn(sk[j][i][0], sk[j][i][1]), sk[j][i][2]);
                hh = __fadd_rn(hh, b2v[j]);
                hh = hh > 0.f ? hh : 0.f;
                h1s[(ly*4 + j)*H2STR + u0 + i] = hh;
            }
        __syncthreads();

        // reducer: all 128 threads ingest T_SUB t's in order into numpy leaves
        // (chunked loads of 8; add order is strict sequential -> bit-exact)
        {
            for (int g = 0; g < T_SUB; g += 8) {
                float v[8];
#pragma unroll
                for (int m = 0; m < 8; ++m)
                    v[m] = h1s[tid*H2STR + g + m];
#pragma unroll
                for (int m = 0; m < 8; ++m) {
                    float vv = v[m];
                    int j = leaf_pos & 7;
                    racc[j] = (leaf_pos < 8) ? vv : __fadd_rn(racc[j], vv);
                    ++leaf_pos;
                    int llen = (leaf_id == 7) ? 112 : 104;
                    if (leaf_pos == llen) {
                        leafs[tid*8 + leaf_id] = np8_combine(racc);
                        ++leaf_id; leaf_pos = 0;
                    }
                }
            }
        }
        __syncthreads();   // reducer done before next tile's phase A writes h1s
    }

    // numpy pairwise-840 recombination
    {
        const float* L = &leafs[tid*8];
        float s0 = __fadd_rn(L[0], L[1]);
        float s1 = __fadd_rn(L[2], L[3]);
        float sA = __fadd_rn(s0, s1);
        float s2 = __fadd_rn(L[4], L[5]);
        float s3 = __fadd_rn(L[6], L[7]);
        float sB = __fadd_rn(s2, s3);
        float tot = __fadd_rn(sA, sB);
        zout[(size_t)b*LAT + tid] = __fdiv_rn(tot, 840.0f);
    }
}

// ---------------- RVQ, numpy-f32 bit-faithful ----------------
__global__ __launch_bounds__(256) void rvq32_kernel(
    const float* __restrict__ cb, const float* __restrict__ z,
    float* __restrict__ zqout, float* __restrict__ oidx)
{
    __shared__ float rr[LAT];
    __shared__ float Ash;
    __shared__ float redd[256];
    __shared__ int   rede[256];
    __shared__ float sredd[64];
    __shared__ int   srede[64];
    __shared__ int   beste;
    __shared__ float qv[NQ * LAT];

    const int tid = threadIdx.x;
    const int b   = blockIdx.x;

    if (tid < LAT) rr[tid] = z[(size_t)b*LAT + tid];
    __syncthreads();

    for (int q = 0; q < NQ; ++q) {
        const float* __restrict__ cbq = cb + (size_t)q * NEMB * LAT;

        if (tid == 0) {
            float r8[8];
#pragma unroll
            for (int j = 0; j < 8; ++j) r8[j] = __fmul_rn(rr[j], rr[j]);
            for (int i = 8; i < LAT; i += 8)
#pragma unroll
                for (int j = 0; j < 8; ++j)
                    r8[j] = __fadd_rn(r8[j], __fmul_rn(rr[i+j], rr[i+j]));
            Ash = np8_combine(r8);
        }
        __syncthreads();

        float dmin = 0.f; int emin = 0;
#pragma unroll
        for (int h = 0; h < 2; ++h) {
            int e = 2*tid + h;
            const float* __restrict__ cp = cbq + (size_t)e*LAT;
            float dot = 0.f;
            float c8[8];
#pragma unroll
            for (int j = 0; j < 8; ++j) {
                float c = cp[j];
                c8[j] = __fmul_rn(c, c);
                dot = __fmaf_rn(c, rr[j], dot);
            }
            for (int i = 8; i < LAT; i += 8)
#pragma unroll
                for (int j = 0; j < 8; ++j) {
                    float c = cp[i+j];
                    dot = __fmaf_rn(c, rr[i+j], dot);
                    c8[j] = __fadd_rn(c8[j], __fmul_rn(c, c));
                }
            float cn = np8_combine(c8);
            float G  = __fmul_rn(2.0f, dot);
            float d  = __fadd_rn(__fsub_rn(Ash, G), cn);
            if (h == 0) { dmin = d; emin = e; }
            else if (d < dmin) { dmin = d; emin = e; }
        }
        redd[tid] = dmin; rede[tid] = emin;
        __syncthreads();

        if (tid < 64) {
            float bb = redd[tid*4]; int ee = rede[tid*4];
            for (int j = 1; j < 4; ++j) {
                float dj = redd[tid*4 + j];
                if (dj < bb) { bb = dj; ee = rede[tid*4 + j]; }
            }
            sredd[tid] = bb; srede[tid] = ee;
        }
        __syncthreads();
        if (tid == 0) {
            float bb = sredd[0]; int ee = srede[0];
            for (int j = 1; j < 64; ++j) {
                float dj = sredd[j];
                if (dj < bb) { bb = dj; ee = srede[j]; }
            }
            beste = ee;
            oidx[(size_t)b*NQ + q] = (float)ee;
        }
        __syncthreads();

        if (tid < LAT) {
            float cv = cbq[(size_t)beste*LAT + tid];
            qv[q*LAT + tid] = cv;
            rr[tid] = __fsub_rn(rr[tid], cv);
        }
        __syncthreads();
    }

    if (tid < LAT) {
        float s = qv[tid];
        for (int s2 = 1; s2 < NQ; ++s2)
            s = __fadd_rn(s, qv[s2*LAT + tid]);
        zqout[(size_t)b*LAT + tid] = s;
    }
}

extern "C" void kernel_launch(void* const* d_in, const int* in_sizes, int n_in,
                              void* d_out, int out_size, void* d_ws, size_t ws_size,
                              hipStream_t stream)
{
    (void)in_sizes; (void)n_in; (void)out_size;
    const float* x  = (const float*)d_in[0];
    const float* w1 = (const float*)d_in[1];
    const float* b1 = (const float*)d_in[2];
    const float* w2 = (const float*)d_in[3];
    const float* b2 = (const float*)d_in[4];
    const float* cb = (const float*)d_in[5];

    float* out  = (float*)d_out;
    float* zq   = out;                         // 2048*1*128 floats
    float* oidx = out + (size_t)B_SZ * LAT;    // 2048*1*12 floats

    const size_t w2r_bytes = (size_t)HID * 384 * sizeof(float);  // 393216

    if (ws_size >= w2r_bytes) {
        float* w2r = (float*)d_ws;
        w2r_kernel<<<(HID*384 + 255)/256, 256, 0, stream>>>(w2, w2r);
        enc_kernel<1><<<B_SZ, 128, 0, stream>>>(x, w1, b1, w2, w2r, b2, zq);
    } else {
        enc_kernel<0><<<B_SZ, 128, 0, stream>>>(x, w1, b1, w2, nullptr, b2, zq);
    }
    rvq32_kernel<<<B_SZ, 256, 0, stream>>>(cb, zq, zq, oidx);
}

// Round 8
// 5516.753 us; speedup vs baseline: 1.6209x; 1.0740x over previous
//
#include <hip/hip_runtime.h>

#define B_SZ 2048
#define FEAT 840
#define HID  256
#define LAT  128
#define NQ   12
#define NEMB 512

#define T_SUB 40    // 21 tiles x 40 = 840
#define NTILE 21
#define HSTR  46    // h1 row stride (40+2 halo, padded EVEN -> float2 reads align)
#define H2STR 21    // h2 stage stride (20 t's +1, ODD -> reducer conflict-free)
#define CQ    64    // c2 quarter: h1 slab holds 64 channels at a time
#define HBUF  (CQ * HSTR)   // 2944 floats; h2 stage (128*21=2688) aliases here

#define W2R_FLOATS ((size_t)HID * 384)   // 98304
#define CBN_FLOATS ((size_t)NQ * NEMB)   // 6144

// numpy pairwise 8-accumulator combine: ((r0+r1)+(r2+r3))+((r4+r5)+(r6+r7))
__device__ __forceinline__ float np8_combine(const float* r) {
    float sA = __fadd_rn(r[0], r[1]);
    float sB = __fadd_rn(r[2], r[3]);
    float sC = __fadd_rn(r[4], r[5]);
    float sD = __fadd_rn(r[6], r[7]);
    return __fadd_rn(__fadd_rn(sA, sB), __fadd_rn(sC, sD));
}

// ---------------- w2 repack, j-major: w2r[c2][ly][j*3+k] ----------------
__global__ __launch_bounds__(256) void w2r_kernel(const float* __restrict__ w2,
                                                  float* __restrict__ w2r)
{
    int p = blockIdx.x * 256 + threadIdx.x;          // [0, 256*384)
    if (p >= HID * 384) return;
    int c2 = p / 384, r = p - c2 * 384;
    int ly = r / 12, jk = r - ly * 12;
    int j = jk / 3, k = jk - j * 3;
    w2r[p] = w2[(size_t)(ly*4 + j)*768 + c2*3 + k];
}

// ---- codebook norms, EXACT same c8/np8 op order as the inline rvq path ----
__global__ __launch_bounds__(256) void cbn_kernel(const float* __restrict__ cb,
                                                  float* __restrict__ cbn)
{
    int p = blockIdx.x * 256 + threadIdx.x;          // [0, NQ*NEMB)
    if (p >= NQ * NEMB) return;
    const float* __restrict__ cp = cb + (size_t)p * LAT;
    float c8[8];
#pragma unroll
    for (int j = 0; j < 8; ++j) {
        float c = cp[j];
        c8[j] = __fmul_rn(c, c);
    }
    for (int i = 8; i < LAT; i += 8)
#pragma unroll
        for (int j = 0; j < 8; ++j) {
            float c = cp[i+j];
            c8[j] = __fadd_rn(c8[j], __fmul_rn(c, c));
        }
    cbn[p] = np8_combine(c8);
}

// ---------------- encoder, numpy-f32 bit-faithful ----------------
// 128 threads = 2 waves. Thread (ly = tid>>2, tx = tid&3) owns output
// channels l = ly*4..ly*4+3 at t-positions u0..u0+9: 120 accumulators,
// 12 weight floats feed 120 FMAs (round-7's winning density, unchanged).
// NEW vs r7: c2 in FOUR quarters of 64 (h1 slab 11.8 KB) and h2/reduce in
// TWO 20-t stages (h2 tile 10.5 KB, aliased) -> LDS 19.25 KB -> 8 blocks/CU
// (16 waves/CU at VGPR<=128), up from 5 blocks -- hides the w2r L2 latency.
// acc carried across quarters -> per-(l,t,k) fma chain c2 = 0..255 ascending;
// reducer ingests t strictly 0..39 per tile across the 2 stages: bit-exact.
// (Round-1 lesson: NO min-waves launch-bounds arg.)
template <int USE_WR>
__global__ __launch_bounds__(128) void enc_kernel(
    const float* __restrict__ x,  const float* __restrict__ w1,
    const float* __restrict__ b1, const float* __restrict__ w2,
    const float* __restrict__ w2r,
    const float* __restrict__ b2, float* __restrict__ zout)
{
    __shared__ float xp[FEAT + 4];          // 3376 B
    __shared__ float h1s[HBUF];             // 11776 B; h2 stages alias here
    __shared__ float leafs[LAT * 8];        // 4096 B   => 19248 B total

    const int tid = threadIdx.x;            // [0,128)
    const int b   = blockIdx.x;
    const int tx  = tid & 3;                // t-group (10 t's)
    const int ly  = tid >> 2;               // l-group (4 l's)
    const int u0  = tx * 10;

    // phase-A mapping: channel-in-quarter = tid>>1, tap-piece = tid&1 (21 taps)
    const int ach   = tid >> 1;
    const int piece = tid & 1;

    float b2v[4];
#pragma unroll
    for (int j = 0; j < 4; ++j) b2v[j] = b2[ly*4 + j];

    for (int i = tid; i < FEAT + 2; i += 128)
        xp[i] = (i >= 1 && i <= FEAT) ? x[(size_t)b*FEAT + i - 1] : 0.f;

    // numpy pairwise-840 leaf state (all 128 threads, one l each)
    float racc[8];
    int leaf_id = 0, leaf_pos = 0;
#pragma unroll
    for (int j = 0; j < 8; ++j) racc[j] = 0.f;

    __syncthreads();
    for (int t0 = 0; t0 < FEAT; t0 += T_SUB) {
        const bool edge = (t0 == 0) | (t0 + T_SUB == FEAT);

        float sk[4][10][3];
#pragma unroll
        for (int j = 0; j < 4; ++j)
#pragma unroll
            for (int i = 0; i < 10; ++i)
#pragma unroll
                for (int k = 0; k < 3; ++k) sk[j][i][k] = 0.f;

#pragma unroll 1
        for (int qf = 0; qf < 4; ++qf) {
            // ---- phase A (quarter qf): h1[ach][tp], this thread's 21 taps ----
            {
                const int c = qf*CQ + ach;
                const float wA = w1[c*3+0], wB = w1[c*3+1], wC = w1[c*3+2];
                const float bb = b1[c];
                const int tpb = piece * 21;
                if (edge) {
                    for (int tp = tpb; tp < tpb + 21; ++tp) {
                        int tg = t0 - 1 + tp;
                        float v = 0.f;
                        if (tg >= 0 && tg < FEAT) {
                            float s = __fadd_rn(__fadd_rn(__fmul_rn(wA, xp[tg]),
                                                          __fmul_rn(wB, xp[tg+1])),
                                                __fmul_rn(wC, xp[tg+2]));
                            s = __fadd_rn(s, bb);
                            v = s > 0.f ? s : 0.f;
                        }
                        h1s[ach*HSTR + tp] = v;
                    }
                } else {
#pragma unroll 7
                    for (int tp = tpb; tp < tpb + 21; ++tp) {
                        int tg = t0 - 1 + tp;
                        float s = __fadd_rn(__fadd_rn(__fmul_rn(wA, xp[tg]),
                                                      __fmul_rn(wB, xp[tg+1])),
                                            __fmul_rn(wC, xp[tg+2]));
                        s = __fadd_rn(s, bb);
                        h1s[ach*HSTR + tp] = s > 0.f ? s : 0.f;
                    }
                }
            }
            __syncthreads();

            // ---- phase B (quarter qf): c2 = qf*64 + cc ascending ----
            if (USE_WR) {
                const float* __restrict__ wbase =
                    w2r + (size_t)(qf*CQ)*384 + ly*12;
#pragma unroll 2
                for (int cc = 0; cc < CQ; ++cc) {
                    const float4* __restrict__ wq =
                        (const float4*)(wbase + (size_t)cc*384);
                    float4 A0 = wq[0], A1 = wq[1], A2 = wq[2];
                    float w_[12];
                    w_[0]=A0.x; w_[1]=A0.y; w_[2]=A0.z; w_[3]=A0.w;
                    w_[4]=A1.x; w_[5]=A1.y; w_[6]=A1.z; w_[7]=A1.w;
                    w_[8]=A2.x; w_[9]=A2.y; w_[10]=A2.z; w_[11]=A2.w;

                    const float2* __restrict__ hq =
                        (const float2*)(&h1s[cc*HSTR + u0]);   // even idx: aligned
                    float2 q0=hq[0], q1=hq[1], q2=hq[2], q3=hq[3], q4=hq[4], q5=hq[5];
                    float hv[12] = {q0.x,q0.y,q1.x,q1.y,q2.x,q2.y,
                                    q3.x,q3.y,q4.x,q4.y,q5.x,q5.y};
#pragma unroll
                    for (int j = 0; j < 4; ++j)
#pragma unroll
                        for (int i = 0; i < 10; ++i)
#pragma unroll
                            for (int k = 0; k < 3; ++k)
                                sk[j][i][k] = __fmaf_rn(w_[j*3+k], hv[i+k],
                                                        sk[j][i][k]);
                }
            } else {
                for (int cc = 0; cc < CQ; ++cc) {
                    int c2 = qf*CQ + cc;
                    const float* hp = &h1s[cc*HSTR + u0];
                    float hv[12];
#pragma unroll
                    for (int m = 0; m < 12; ++m) hv[m] = hp[m];
#pragma unroll
                    for (int j = 0; j < 4; ++j) {
                        float wa = w2[(size_t)(ly*4+j)*768 + c2*3 + 0];
                        float wb = w2[(size_t)(ly*4+j)*768 + c2*3 + 1];
                        float wc = w2[(size_t)(ly*4+j)*768 + c2*3 + 2];
#pragma unroll
                        for (int i = 0; i < 10; ++i) {
                            sk[j][i][0] = __fmaf_rn(wa, hv[i],   sk[j][i][0]);
                            sk[j][i][1] = __fmaf_rn(wb, hv[i+1], sk[j][i][1]);
                            sk[j][i][2] = __fmaf_rn(wc, hv[i+2], sk[j][i][2]);
                        }
                    }
                }
            }
            __syncthreads();   // h1s reads done before next quarter / h2 alias
        }

        // h2 + reduce in two 20-t stages (aliased into h1s region).
        // stage st: threads with tx>>1 == st write their t's; then all 128
        // threads ingest t = st*20 .. st*20+19 in order -> sequential 0..39.
#pragma unroll 1
        for (int st = 0; st < 2; ++st) {
            if ((tx >> 1) == st) {
#pragma unroll
                for (int j = 0; j < 4; ++j)
#pragma unroll
                    for (int i = 0; i < 10; ++i) {
                        float hh = __fadd_rn(__fadd_rn(sk[j][i][0], sk[j][i][1]),
                                             sk[j][i][2]);
                        hh = __fadd_rn(hh, b2v[j]);
                        hh = hh > 0.f ? hh : 0.f;
                        h1s[(ly*4 + j)*H2STR + (u0 - st*20) + i] = hh;
                    }
            }
            __syncthreads();   // h2 stage visible to reducer

            for (int g = 0; g < 20; g += 10) {
                float v[10];
#pragma unroll
                for (int m = 0; m < 10; ++m)
                    v[m] = h1s[tid*H2STR + g + m];
#pragma unroll
                for (int m = 0; m < 10; ++m) {
                    float vv = v[m];
                    int j = leaf_pos & 7;
                    racc[j] = (leaf_pos < 8) ? vv : __fadd_rn(racc[j], vv);
                    ++leaf_pos;
                    int llen = (leaf_id == 7) ? 112 : 104;
                    if (leaf_pos == llen) {
                        leafs[tid*8 + leaf_id] = np8_combine(racc);
                        ++leaf_id; leaf_pos = 0;
                    }
                }
            }
            __syncthreads();   // reducer reads done before next stage/tile write
        }
    }

    // numpy pairwise-840 recombination
    {
        const float* L = &leafs[tid*8];
        float s0 = __fadd_rn(L[0], L[1]);
        float s1 = __fadd_rn(L[2], L[3]);
        float sA = __fadd_rn(s0, s1);
        float s2 = __fadd_rn(L[4], L[5]);
        float s3 = __fadd_rn(L[6], L[7]);
        float sB = __fadd_rn(s2, s3);
        float tot = __fadd_rn(sA, sB);
        zout[(size_t)b*LAT + tid] = __fdiv_rn(tot, 840.0f);
    }
}

// ---------------- RVQ, numpy-f32 bit-faithful ----------------
// USE_CN: codebook norms precomputed by cbn_kernel with the byte-identical
// c8/np8 op sequence -> cn values bit-equal to the inline computation.
// dot chain order untouched in both paths.
template <int USE_CN>
__global__ __launch_bounds__(256) void rvq32_kernel(
    const float* __restrict__ cb, const float* __restrict__ cbn,
    const float* __restrict__ z,
    float* __restrict__ zqout, float* __restrict__ oidx)
{
    __shared__ float rr[LAT];
    __shared__ float Ash;
    __shared__ float redd[256];
    __shared__ int   rede[256];
    __shared__ float sredd[64];
    __shared__ int   srede[64];
    __shared__ int   beste;
    __shared__ float qv[NQ * LAT];

    const int tid = threadIdx.x;
    const int b   = blockIdx.x;

    if (tid < LAT) rr[tid] = z[(size_t)b*LAT + tid];
    __syncthreads();

    for (int q = 0; q < NQ; ++q) {
        const float* __restrict__ cbq = cb + (size_t)q * NEMB * LAT;

        if (tid == 0) {
            float r8[8];
#pragma unroll
            for (int j = 0; j < 8; ++j) r8[j] = __fmul_rn(rr[j], rr[j]);
            for (int i = 8; i < LAT; i += 8)
#pragma unroll
                for (int j = 0; j < 8; ++j)
                    r8[j] = __fadd_rn(r8[j], __fmul_rn(rr[i+j], rr[i+j]));
            Ash = np8_combine(r8);
        }
        __syncthreads();

        float dmin = 0.f; int emin = 0;
#pragma unroll
        for (int h = 0; h < 2; ++h) {
            int e = 2*tid + h;
            const float* __restrict__ cp = cbq + (size_t)e*LAT;
            float dot = 0.f;
            float cn;
            if (USE_CN) {
#pragma unroll
                for (int j = 0; j < 8; ++j)
                    dot = __fmaf_rn(cp[j], rr[j], dot);
                for (int i = 8; i < LAT; i += 8)
#pragma unroll
                    for (int j = 0; j < 8; ++j)
                        dot = __fmaf_rn(cp[i+j], rr[i+j], dot);
                cn = cbn[(size_t)q*NEMB + e];
            } else {
                float c8[8];
#pragma unroll
                for (int j = 0; j < 8; ++j) {
                    float c = cp[j];
                    c8[j] = __fmul_rn(c, c);
                    dot = __fmaf_rn(c, rr[j], dot);
                }
                for (int i = 8; i < LAT; i += 8)
#pragma unroll
                    for (int j = 0; j < 8; ++j) {
                        float c = cp[i+j];
                        dot = __fmaf_rn(c, rr[i+j], dot);
                        c8[j] = __fadd_rn(c8[j], __fmul_rn(c, c));
                    }
                cn = np8_combine(c8);
            }
            float G  = __fmul_rn(2.0f, dot);
            float d  = __fadd_rn(__fsub_rn(Ash, G), cn);
            if (h == 0) { dmin = d; emin = e; }
            else if (d < dmin) { dmin = d; emin = e; }
        }
        redd[tid] = dmin; rede[tid] = emin;
        __syncthreads();

        if (tid < 64) {
            float bb = redd[tid*4]; int ee = rede[tid*4];
            for (int j = 1; j < 4; ++j) {
                float dj = redd[tid*4 + j];
                if (dj < bb) { bb = dj; ee = rede[tid*4 + j]; }
            }
            sredd[tid] = bb; srede[tid] = ee;
        }
        __syncthreads();
        if (tid == 0) {
            float bb = sredd[0]; int ee = srede[0];
            for (int j = 1; j < 64; ++j) {
                float dj = sredd[j];
                if (dj < bb) { bb = dj; ee = srede[j]; }
            }
            beste = ee;
            oidx[(size_t)b*NQ + q] = (float)ee;
        }
        __syncthreads();

        if (tid < LAT) {
            float cv = cbq[(size_t)beste*LAT + tid];
            qv[q*LAT + tid] = cv;
            rr[tid] = __fsub_rn(rr[tid], cv);
        }
        __syncthreads();
    }

    if (tid < LAT) {
        float s = qv[tid];
        for (int s2 = 1; s2 < NQ; ++s2)
            s = __fadd_rn(s, qv[s2*LAT + tid]);
        zqout[(size_t)b*LAT + tid] = s;
    }
}

extern "C" void kernel_launch(void* const* d_in, const int* in_sizes, int n_in,
                              void* d_out, int out_size, void* d_ws, size_t ws_size,
                              hipStream_t stream)
{
    (void)in_sizes; (void)n_in; (void)out_size;
    const float* x  = (const float*)d_in[0];
    const float* w1 = (const float*)d_in[1];
    const float* b1 = (const float*)d_in[2];
    const float* w2 = (const float*)d_in[3];
    const float* b2 = (const float*)d_in[4];
    const float* cb = (const float*)d_in[5];

    float* out  = (float*)d_out;
    float* zq   = out;                         // 2048*1*128 floats
    float* oidx = out + (size_t)B_SZ * LAT;    // 2048*1*12 floats

    const size_t w2r_bytes  = W2R_FLOATS * sizeof(float);                 // 393216
    const size_t full_bytes = (W2R_FLOATS + CBN_FLOATS) * sizeof(float);  // 417792

    if (ws_size >= full_bytes) {
        float* w2r = (float*)d_ws;
        float* cbn = (float*)d_ws + W2R_FLOATS;
        w2r_kernel<<<(HID*384 + 255)/256, 256, 0, stream>>>(w2, w2r);
        cbn_kernel<<<(NQ*NEMB + 255)/256, 256, 0, stream>>>(cb, cbn);
        enc_kernel<1><<<B_SZ, 128, 0, stream>>>(x, w1, b1, w2, w2r, b2, zq);
        rvq32_kernel<1><<<B_SZ, 256, 0, stream>>>(cb, cbn, zq, zq, oidx);
    } else if (ws_size >= w2r_bytes) {
        float* w2r = (float*)d_ws;
        w2r_kernel<<<(HID*384 + 255)/256, 256, 0, stream>>>(w2, w2r);
        enc_kernel<1><<<B_SZ, 128, 0, stream>>>(x, w1, b1, w2, w2r, b2, zq);
        rvq32_kernel<0><<<B_SZ, 256, 0, stream>>>(cb, nullptr, zq, zq, oidx);
    } else {
        enc_kernel<0><<<B_SZ, 128, 0, stream>>>(x, w1, b1, w2, nullptr, b2, zq);
        rvq32_kernel<0><<<B_SZ, 256, 0, stream>>>(cb, nullptr, zq, zq, oidx);
    }
}